// Round 1
// baseline (147.150 us; speedup 1.0000x reference)
//
#include <hip/hip_runtime.h>

typedef unsigned int uint;
typedef unsigned short ushort;
typedef __attribute__((ext_vector_type(8))) short short8;
typedef __attribute__((ext_vector_type(4))) float f32x4;
typedef __attribute__((ext_vector_type(4))) float float4v;
typedef __attribute__((ext_vector_type(4))) ushort ushort4v;

constexpr int Edim = 768;
constexpr int Kdim = 768;   // C*P*P = 3*16*16
constexpr int Mdim = 25088; // B*Npatch = 128*196
constexpr int BM = 128, BN = 128, BK = 64;
constexpr int KSTEPS = Kdim / BK; // 12

// round-to-nearest-even f32 -> bf16
__device__ __forceinline__ ushort f2bf(float f) {
  uint u = __float_as_uint(f);
  return (ushort)((u + 0x7fffu + ((u >> 16) & 1u)) >> 16);
}

// ---------------- Phase 1: weight quantization ----------------
// one block per output channel e
__global__ void prep_kernel(const float* __restrict__ weight,
                            const float* __restrict__ bias,
                            const float* __restrict__ sfin,
                            ushort* __restrict__ w_int,   // [E][K] bf16
                            float* __restrict__ w_sf,     // [E]
                            float* __restrict__ bias_out) // [E] = b_int*conv_sf
{
  __shared__ float red[256];
  const int e = blockIdx.x, t = threadIdx.x;
  const float* wrow = weight + e * Kdim;
  float mx = 0.f;
  for (int k = t; k < Kdim; k += 256) mx = fmaxf(mx, fabsf(wrow[k]));
  red[t] = mx;
  __syncthreads();
  for (int s = 128; s > 0; s >>= 1) {
    if (t < s) red[t] = fmaxf(red[t], red[t + s]);
    __syncthreads();
  }
  const float sf = red[0] / 127.0f;
  for (int k = t; k < Kdim; k += 256)
    w_int[e * Kdim + k] = f2bf(rintf(wrow[k] / sf)); // integers <=127, exact in bf16
  if (t == 0) {
    float conv = sf * sfin[0];
    w_sf[e] = sf;
    bias_out[e] = rintf(bias[e] / conv) * conv;
  }
}

// ---------------- Phase 2: MFMA GEMM + global absmax ----------------
// out[m,e] = (sum_d x_patch[m,d]*w_int[e,d]) * w_sf[e] + bias_out[e]
// A[m,d]: m = b*196 + gh*14 + gw ; d = c*256 + ph*16 + pw
//   x flat: b*150528 + c*50176 + (gh*16+ph)*224 + gw*16 + pw
__global__ __launch_bounds__(256) void gemm_kernel(
    const float* __restrict__ x, const ushort* __restrict__ w_int,
    const float* __restrict__ w_sf, const float* __restrict__ bias_out,
    float* __restrict__ out, uint* __restrict__ amax_bits) {
  __shared__ __align__(16) ushort As[BM * BK]; // [row 128][k 64], XOR-swizzled 16B chunks
  __shared__ __align__(16) ushort Bs[BN * BK]; // [e   128][k 64], same swizzle

  const int t = threadIdx.x;
  const int m0 = blockIdx.x * BM;
  const int e0 = blockIdx.y * BN;

  // --- A staging precompute: 8 passes, thread handles float4 (i = t&15 fixed)
  const int ai = t & 15;
  int abase[8], alds[8];
#pragma unroll
  for (int p = 0; p < 8; ++p) {
    int r = p * 16 + (t >> 4);
    int m = m0 + r;
    int bb = m / 196;
    int n = m - bb * 196;
    int gh = n / 14;
    int gw = n - gh * 14;
    abase[p] = bb * 150528 + gh * 3584 + gw * 16 + (ai >> 2) * 224 + (ai & 3) * 4;
    alds[p] = r * 64 + (((ai >> 1) ^ (r & 7)) << 3) + ((ai & 1) << 2);
  }
  // --- B staging precompute: 4 passes, 16B chunk each
  int bgl[4], blds[4];
#pragma unroll
  for (int p = 0; p < 4; ++p) {
    int r = p * 32 + (t >> 3);
    int c = t & 7;
    bgl[p] = (e0 + r) * Kdim + c * 8;
    blds[p] = r * 64 + ((c ^ (r & 7)) << 3);
  }

  const int lane = t & 63;
  const int wv = t >> 6;
  const int wrow0 = (wv >> 1) * 64; // wave tile origin within block tile
  const int wcol0 = (wv & 1) * 64;
  const int l15 = lane & 15, l4 = lane >> 4;
  int arow[4], brow[4];
#pragma unroll
  for (int i = 0; i < 4; ++i) {
    arow[i] = wrow0 + i * 16 + l15;
    brow[i] = wcol0 + i * 16 + l15;
  }

  f32x4 acc[4][4] = {};

  for (int kb = 0; kb < KSTEPS; ++kb) {
    __syncthreads();
    // stage A: 128 rows x 64 k f32 -> bf16 (channel c = kb/4, ph0 = (kb%4)*4)
    const float* src = x + (kb >> 2) * 50176 + (kb & 3) * 896;
#pragma unroll
    for (int p = 0; p < 8; ++p) {
      float4v v = *(const float4v*)(src + abase[p]);
      ushort4v u;
      u.x = f2bf(v.x); u.y = f2bf(v.y); u.z = f2bf(v.z); u.w = f2bf(v.w);
      *(ushort4v*)&As[alds[p]] = u;
    }
    // stage B: 128 e-rows x 64 k bf16
    const ushort* wsrc = w_int + kb * 64;
#pragma unroll
    for (int p = 0; p < 4; ++p)
      *(short8*)&Bs[blds[p]] = *(const short8*)(wsrc + bgl[p]);
    __syncthreads();

#pragma unroll
    for (int kk = 0; kk < 2; ++kk) {
      short8 a[4], b[4];
      const int cb = kk * 4 + l4; // 16B chunk index for this lane group
#pragma unroll
      for (int i = 0; i < 4; ++i)
        a[i] = *(const short8*)&As[arow[i] * 64 + ((cb ^ (arow[i] & 7)) << 3)];
#pragma unroll
      for (int i = 0; i < 4; ++i)
        b[i] = *(const short8*)&Bs[brow[i] * 64 + ((cb ^ (brow[i] & 7)) << 3)];
#pragma unroll
      for (int mi = 0; mi < 4; ++mi)
#pragma unroll
        for (int ni = 0; ni < 4; ++ni)
          acc[mi][ni] = __builtin_amdgcn_mfma_f32_16x16x32_bf16(
              a[mi], b[ni], acc[mi][ni], 0, 0, 0);
    }
  }

  // epilogue: scale + bias, track absmax, store f32
  float amax = 0.f;
#pragma unroll
  for (int ni = 0; ni < 4; ++ni) {
    const int e = e0 + wcol0 + ni * 16 + l15;
    const float s = w_sf[e], bo = bias_out[e];
#pragma unroll
    for (int mi = 0; mi < 4; ++mi) {
      const int mr = m0 + wrow0 + mi * 16 + l4 * 4;
#pragma unroll
      for (int q = 0; q < 4; ++q) {
        float v = acc[mi][ni][q] * s + bo;
        amax = fmaxf(amax, fabsf(v));
        out[(mr + q) * Edim + e] = v;
      }
    }
  }
#pragma unroll
  for (int off = 32; off > 0; off >>= 1)
    amax = fmaxf(amax, __shfl_xor(amax, off));
  if (lane == 0) atomicMax(amax_bits, __float_as_uint(amax));
}

// ---------------- Phase 3: requantize in place + write act_sf ----------------
__global__ void requant_kernel(float* __restrict__ out,
                               const uint* __restrict__ amax_bits,
                               float* __restrict__ sf_out, int n4) {
  const float mx = __uint_as_float(*amax_bits);
  const float act_sf = mx / 127.0f;
  const float inv = 127.0f / mx;
  const int idx = blockIdx.x * blockDim.x + threadIdx.x;
  if (idx == 0) *sf_out = act_sf;
  float4v* o = (float4v*)out;
  const int stride = gridDim.x * blockDim.x;
  for (int i = idx; i < n4; i += stride) {
    float4v v = o[i];
    v.x = rintf(v.x * inv) * act_sf;
    v.y = rintf(v.y * inv) * act_sf;
    v.z = rintf(v.z * inv) * act_sf;
    v.w = rintf(v.w * inv) * act_sf;
    o[i] = v;
  }
}

extern "C" void kernel_launch(void* const* d_in, const int* in_sizes, int n_in,
                              void* d_out, int out_size, void* d_ws, size_t ws_size,
                              hipStream_t stream) {
  const float* x = (const float*)d_in[0];
  const float* weight = (const float*)d_in[1];
  const float* bias = (const float*)d_in[2];
  const float* sfin = (const float*)d_in[3];
  float* out = (float*)d_out;

  uint* amax_bits = (uint*)d_ws;
  ushort* w_int = (ushort*)((char*)d_ws + 16);
  float* w_sf = (float*)((char*)d_ws + 16 + Edim * Kdim * 2);
  float* bias_out = w_sf + Edim;

  hipMemsetAsync(d_ws, 0, 4, stream); // zero amax accumulator each call

  prep_kernel<<<Edim, 256, 0, stream>>>(weight, bias, sfin, w_int, w_sf, bias_out);

  dim3 grid(Mdim / BM, Edim / BN); // 196 x 6
  gemm_kernel<<<grid, 256, 0, stream>>>(x, w_int, w_sf, bias_out, out, amax_bits);

  const int n4 = (out_size - 1) / 4;
  requant_kernel<<<2048, 256, 0, stream>>>(out, amax_bits, out + (out_size - 1), n4);
}

// Round 2
// 144.606 us; speedup vs baseline: 1.0176x; 1.0176x over previous
//
#include <hip/hip_runtime.h>

typedef unsigned int uint;
typedef unsigned short ushort;
typedef __attribute__((ext_vector_type(8))) short short8;
typedef __attribute__((ext_vector_type(4))) float f32x4;
typedef __attribute__((ext_vector_type(4))) float float4v;
typedef __attribute__((ext_vector_type(4))) ushort ushort4v;

constexpr int Edim = 768;
constexpr int Kdim = 768;   // C*P*P
constexpr int Mdim = 25088; // B*Npatch
constexpr int BM = 128, BN = 128, BK = 64;
constexpr int KSTEPS = Kdim / BK; // 12

// ws layout
constexpr size_t WS_AMAX = 0;
constexpr size_t WS_WSF = 1024;
constexpr size_t WS_BIAS = 4096;
constexpr size_t WS_WINT = 8192;                       // 768*768*2 = 1179648
constexpr size_t WS_APAT = 8192 + 1179648;             // 25088*768*2 = 38535168
constexpr size_t WS_NEED_FULL = WS_APAT + (size_t)Mdim * Kdim * 2;
constexpr size_t WS_NEED_MIN = WS_APAT;

// round-to-nearest-even f32 -> bf16
__device__ __forceinline__ ushort f2bf(float f) {
  uint u = __float_as_uint(f);
  return (ushort)((u + 0x7fffu + ((u >> 16) & 1u)) >> 16);
}

__device__ __forceinline__ void gload16(const ushort* g, ushort* l) {
  auto gp = (const __attribute__((address_space(1))) uint*)(const void*)g;
  auto lp = (__attribute__((address_space(3))) uint*)(void*)l;
  __builtin_amdgcn_global_load_lds(gp, lp, 16, 0, 0);
}

// ---------------- weight quantization ----------------
__global__ void prep_kernel(const float* __restrict__ weight,
                            const float* __restrict__ bias,
                            const float* __restrict__ sfin,
                            ushort* __restrict__ w_int,
                            float* __restrict__ w_sf,
                            float* __restrict__ bias_out) {
  __shared__ float red[256];
  const int e = blockIdx.x, t = threadIdx.x;
  const float* wrow = weight + e * Kdim;
  float mx = 0.f;
  for (int k = t; k < Kdim; k += 256) mx = fmaxf(mx, fabsf(wrow[k]));
  red[t] = mx;
  __syncthreads();
  for (int s = 128; s > 0; s >>= 1) {
    if (t < s) red[t] = fmaxf(red[t], red[t + s]);
    __syncthreads();
  }
  const float sf = red[0] / 127.0f;
  for (int k = t; k < Kdim; k += 256)
    w_int[e * Kdim + k] = f2bf(rintf(wrow[k] / sf));
  if (t == 0) {
    float conv = sf * sfin[0];
    w_sf[e] = sf;
    bias_out[e] = rintf(bias[e] / conv) * conv;
  }
}

// ---------------- patchify: x f32 -> A bf16 [M][K] ----------------
__global__ void patchify_kernel(const float* __restrict__ x,
                                ushort* __restrict__ A, int n4) {
  const int stride = gridDim.x * blockDim.x;
  for (int i4 = blockIdx.x * blockDim.x + threadIdx.x; i4 < n4; i4 += stride) {
    const int i = i4 * 4;
    const int w = i % 224;
    const int t1 = i / 224;
    const int h = t1 % 224;
    const int t2 = t1 / 224;
    const int c = t2 % 3;
    const int b = t2 / 3;
    float4v v = *(const float4v*)(x + i);
    ushort4v u;
    u.x = f2bf(v.x); u.y = f2bf(v.y); u.z = f2bf(v.z); u.w = f2bf(v.w);
    const int m = b * 196 + (h >> 4) * 14 + (w >> 4);
    const int d = c * 256 + (h & 15) * 16 + (w & 15);
    *(ushort4v*)(A + m * Kdim + d) = u;
  }
}

// ---------------- GEMM (pre-patchified A), global_load_lds staging ----------------
// LDS logical layout [row][64] bf16; 16B chunk (row,cb) stored at chunk row*8+(cb^(row&7)).
// global_load_lds writes linearly -> pre-swizzle the global source (same XOR involution).
__global__ __launch_bounds__(256) void gemm2_kernel(
    const ushort* __restrict__ A, const ushort* __restrict__ Bw,
    const float* __restrict__ w_sf, const float* __restrict__ bias_out,
    float* __restrict__ out, uint* __restrict__ amax_bits) {
  __shared__ __align__(16) ushort As[BM * BK];
  __shared__ __align__(16) ushort Bs[BN * BK];

  const int t = threadIdx.x;
  const int m0 = blockIdx.x * BM;
  const int e0 = blockIdx.y * BN;

  // staging: linear LDS chunk c = r*256 + t; row = c>>3 = r*32 + (t>>3);
  // stored col s = t&7; logical col cb = s ^ (row&7) = (t&7)^((t>>3)&7)
  const int cbs = (t & 7) ^ ((t >> 3) & 7);
  const ushort* ag = A + (size_t)(m0 + (t >> 3)) * Kdim + cbs * 8;
  const ushort* bg = Bw + (size_t)(e0 + (t >> 3)) * Kdim + cbs * 8;

  const int lane = t & 63;
  const int wv = t >> 6;
  const int wrow0 = (wv >> 1) * 64;
  const int wcol0 = (wv & 1) * 64;
  const int l15 = lane & 15, l4 = lane >> 4;
  int arow[4], brow[4];
#pragma unroll
  for (int i = 0; i < 4; ++i) {
    arow[i] = wrow0 + i * 16 + l15;
    brow[i] = wcol0 + i * 16 + l15;
  }

  f32x4 acc[4][4] = {};

  for (int kb = 0; kb < KSTEPS; ++kb) {
    __syncthreads();
#pragma unroll
    for (int r = 0; r < 4; ++r) {
      gload16(ag + kb * 64 + r * 32 * Kdim, As + (r * 256 + t) * 8);
      gload16(bg + kb * 64 + r * 32 * Kdim, Bs + (r * 256 + t) * 8);
    }
    __syncthreads(); // drains vmcnt -> LDS tiles ready

#pragma unroll
    for (int kk = 0; kk < 2; ++kk) {
      short8 a[4], b[4];
      const int cb = kk * 4 + l4;
#pragma unroll
      for (int i = 0; i < 4; ++i)
        a[i] = *(const short8*)&As[arow[i] * 64 + ((cb ^ (arow[i] & 7)) << 3)];
#pragma unroll
      for (int i = 0; i < 4; ++i)
        b[i] = *(const short8*)&Bs[brow[i] * 64 + ((cb ^ (brow[i] & 7)) << 3)];
#pragma unroll
      for (int mi = 0; mi < 4; ++mi)
#pragma unroll
        for (int ni = 0; ni < 4; ++ni)
          acc[mi][ni] = __builtin_amdgcn_mfma_f32_16x16x32_bf16(
              a[mi], b[ni], acc[mi][ni], 0, 0, 0);
    }
  }

  float amax = 0.f;
#pragma unroll
  for (int ni = 0; ni < 4; ++ni) {
    const int e = e0 + wcol0 + ni * 16 + l15;
    const float s = w_sf[e], bo = bias_out[e];
#pragma unroll
    for (int mi = 0; mi < 4; ++mi) {
      const int mr = m0 + wrow0 + mi * 16 + l4 * 4;
#pragma unroll
      for (int q = 0; q < 4; ++q) {
        float v = acc[mi][ni][q] * s + bo;
        amax = fmaxf(amax, fabsf(v));
        out[(size_t)(mr + q) * Edim + e] = v;
      }
    }
  }
#pragma unroll
  for (int off = 32; off > 0; off >>= 1)
    amax = fmaxf(amax, __shfl_xor(amax, off));
  if (lane == 0) atomicMax(amax_bits, __float_as_uint(amax));
}

// ---------------- fallback fused GEMM (round-1 kernel) ----------------
__global__ __launch_bounds__(256) void gemm_fused_kernel(
    const float* __restrict__ x, const ushort* __restrict__ w_int,
    const float* __restrict__ w_sf, const float* __restrict__ bias_out,
    float* __restrict__ out, uint* __restrict__ amax_bits) {
  __shared__ __align__(16) ushort As[BM * BK];
  __shared__ __align__(16) ushort Bs[BN * BK];

  const int t = threadIdx.x;
  const int m0 = blockIdx.x * BM;
  const int e0 = blockIdx.y * BN;

  const int ai = t & 15;
  int abase[8], alds[8];
#pragma unroll
  for (int p = 0; p < 8; ++p) {
    int r = p * 16 + (t >> 4);
    int m = m0 + r;
    int bb = m / 196;
    int n = m - bb * 196;
    int gh = n / 14;
    int gw = n - gh * 14;
    abase[p] = bb * 150528 + gh * 3584 + gw * 16 + (ai >> 2) * 224 + (ai & 3) * 4;
    alds[p] = r * 64 + (((ai >> 1) ^ (r & 7)) << 3) + ((ai & 1) << 2);
  }
  int bgl[4], blds[4];
#pragma unroll
  for (int p = 0; p < 4; ++p) {
    int r = p * 32 + (t >> 3);
    int c = t & 7;
    bgl[p] = (e0 + r) * Kdim + c * 8;
    blds[p] = r * 64 + ((c ^ (r & 7)) << 3);
  }

  const int lane = t & 63;
  const int wv = t >> 6;
  const int wrow0 = (wv >> 1) * 64;
  const int wcol0 = (wv & 1) * 64;
  const int l15 = lane & 15, l4 = lane >> 4;
  int arow[4], brow[4];
#pragma unroll
  for (int i = 0; i < 4; ++i) {
    arow[i] = wrow0 + i * 16 + l15;
    brow[i] = wcol0 + i * 16 + l15;
  }

  f32x4 acc[4][4] = {};

  for (int kb = 0; kb < KSTEPS; ++kb) {
    __syncthreads();
    const float* src = x + (kb >> 2) * 50176 + (kb & 3) * 896;
#pragma unroll
    for (int p = 0; p < 8; ++p) {
      float4v v = *(const float4v*)(src + abase[p]);
      ushort4v u;
      u.x = f2bf(v.x); u.y = f2bf(v.y); u.z = f2bf(v.z); u.w = f2bf(v.w);
      *(ushort4v*)&As[alds[p]] = u;
    }
    const ushort* wsrc = w_int + kb * 64;
#pragma unroll
    for (int p = 0; p < 4; ++p)
      *(short8*)&Bs[blds[p]] = *(const short8*)(wsrc + bgl[p]);
    __syncthreads();

#pragma unroll
    for (int kk = 0; kk < 2; ++kk) {
      short8 a[4], b[4];
      const int cb = kk * 4 + l4;
#pragma unroll
      for (int i = 0; i < 4; ++i)
        a[i] = *(const short8*)&As[arow[i] * 64 + ((cb ^ (arow[i] & 7)) << 3)];
#pragma unroll
      for (int i = 0; i < 4; ++i)
        b[i] = *(const short8*)&Bs[brow[i] * 64 + ((cb ^ (brow[i] & 7)) << 3)];
#pragma unroll
      for (int mi = 0; mi < 4; ++mi)
#pragma unroll
        for (int ni = 0; ni < 4; ++ni)
          acc[mi][ni] = __builtin_amdgcn_mfma_f32_16x16x32_bf16(
              a[mi], b[ni], acc[mi][ni], 0, 0, 0);
    }
  }

  float amax = 0.f;
#pragma unroll
  for (int ni = 0; ni < 4; ++ni) {
    const int e = e0 + wcol0 + ni * 16 + l15;
    const float s = w_sf[e], bo = bias_out[e];
#pragma unroll
    for (int mi = 0; mi < 4; ++mi) {
      const int mr = m0 + wrow0 + mi * 16 + l4 * 4;
#pragma unroll
      for (int q = 0; q < 4; ++q) {
        float v = acc[mi][ni][q] * s + bo;
        amax = fmaxf(amax, fabsf(v));
        out[(size_t)(mr + q) * Edim + e] = v;
      }
    }
  }
#pragma unroll
  for (int off = 32; off > 0; off >>= 1)
    amax = fmaxf(amax, __shfl_xor(amax, off));
  if (lane == 0) atomicMax(amax_bits, __float_as_uint(amax));
}

// ---------------- requantize in place + act_sf ----------------
__global__ void requant_kernel(float* __restrict__ out,
                               const uint* __restrict__ amax_bits,
                               float* __restrict__ sf_out, int n4) {
  const float mx = __uint_as_float(*amax_bits);
  const float act_sf = mx / 127.0f;
  const float inv = 127.0f / mx;
  const int idx = blockIdx.x * blockDim.x + threadIdx.x;
  if (idx == 0) *sf_out = act_sf;
  float4v* o = (float4v*)out;
  const int stride = gridDim.x * blockDim.x;
  for (int i = idx; i < n4; i += stride) {
    float4v v = o[i];
    v.x = rintf(v.x * inv) * act_sf;
    v.y = rintf(v.y * inv) * act_sf;
    v.z = rintf(v.z * inv) * act_sf;
    v.w = rintf(v.w * inv) * act_sf;
    o[i] = v;
  }
}

extern "C" void kernel_launch(void* const* d_in, const int* in_sizes, int n_in,
                              void* d_out, int out_size, void* d_ws, size_t ws_size,
                              hipStream_t stream) {
  const float* x = (const float*)d_in[0];
  const float* weight = (const float*)d_in[1];
  const float* bias = (const float*)d_in[2];
  const float* sfin = (const float*)d_in[3];
  float* out = (float*)d_out;

  char* ws = (char*)d_ws;
  uint* amax_bits = (uint*)(ws + WS_AMAX);
  float* w_sf = (float*)(ws + WS_WSF);
  float* bias_out = (float*)(ws + WS_BIAS);
  ushort* w_int = (ushort*)(ws + WS_WINT);
  ushort* A = (ushort*)(ws + WS_APAT);

  hipMemsetAsync(d_ws, 0, 4, stream);
  prep_kernel<<<Edim, 256, 0, stream>>>(weight, bias, sfin, w_int, w_sf, bias_out);

  dim3 grid(Mdim / BM, Edim / BN); // 196 x 6
  if (ws_size >= WS_NEED_FULL) {
    const int n4 = (128 * 3 * 224 * 224) / 4;
    patchify_kernel<<<2048, 256, 0, stream>>>(x, A, n4);
    gemm2_kernel<<<grid, 256, 0, stream>>>(A, w_int, w_sf, bias_out, out, amax_bits);
  } else {
    gemm_fused_kernel<<<grid, 256, 0, stream>>>(x, w_int, w_sf, bias_out, out, amax_bits);
  }

  const int n4o = (out_size - 1) / 4;
  requant_kernel<<<2048, 256, 0, stream>>>(out, amax_bits, out + (out_size - 1), n4o);
}

// Round 3
// 137.368 us; speedup vs baseline: 1.0712x; 1.0527x over previous
//
#include <hip/hip_runtime.h>

typedef unsigned int uint;
typedef unsigned short ushort;
typedef __attribute__((ext_vector_type(8))) short short8;
typedef __attribute__((ext_vector_type(4))) float f32x4;
typedef __attribute__((ext_vector_type(4))) float float4v;
typedef __attribute__((ext_vector_type(4))) ushort ushort4v;

constexpr int Edim = 768;
constexpr int Kdim = 768;   // C*P*P
constexpr int Mdim = 25088; // B*Npatch
constexpr int BM = 128, BN = 128, BK = 64;
constexpr int KSTEPS = Kdim / BK; // 12
constexpr int MB_TILES = Mdim / BM; // 196
constexpr int EB_TILES = Edim / BN; // 6
constexpr int NWG = MB_TILES * EB_TILES; // 1176 = 8*147

// ws layout
constexpr size_t WS_AMAX = 0;
constexpr size_t WS_WSF = 1024;
constexpr size_t WS_BIAS = 4096;
constexpr size_t WS_WINT = 8192;           // 768*768*2
constexpr size_t WS_APAT = 8192 + 1179648; // 25088*768*2

// round-to-nearest-even f32 -> bf16
__device__ __forceinline__ ushort f2bf(float f) {
  uint u = __float_as_uint(f);
  return (ushort)((u + 0x7fffu + ((u >> 16) & 1u)) >> 16);
}

__device__ __forceinline__ void gload16(const ushort* g, ushort* l) {
  auto gp = (const __attribute__((address_space(1))) uint*)(const void*)g;
  auto lp = (__attribute__((address_space(3))) uint*)(void*)l;
  __builtin_amdgcn_global_load_lds(gp, lp, 16, 0, 0);
}

// ---------------- weight quantization ----------------
__global__ void prep_kernel(const float* __restrict__ weight,
                            const float* __restrict__ bias,
                            const float* __restrict__ sfin,
                            ushort* __restrict__ w_int,
                            float* __restrict__ w_sf,
                            float* __restrict__ bias_out) {
  __shared__ float red[256];
  const int e = blockIdx.x, t = threadIdx.x;
  const float* wrow = weight + e * Kdim;
  float mx = 0.f;
  for (int k = t; k < Kdim; k += 256) mx = fmaxf(mx, fabsf(wrow[k]));
  red[t] = mx;
  __syncthreads();
  for (int s = 128; s > 0; s >>= 1) {
    if (t < s) red[t] = fmaxf(red[t], red[t + s]);
    __syncthreads();
  }
  const float sf = red[0] / 127.0f;
  for (int k = t; k < Kdim; k += 256)
    w_int[e * Kdim + k] = f2bf(rintf(wrow[k] / sf));
  if (t == 0) {
    float conv = sf * sfin[0];
    w_sf[e] = sf;
    bias_out[e] = rintf(bias[e] / conv) * conv;
  }
}

// ---------------- patchify: x f32 -> A bf16 [M][K] ----------------
__global__ void patchify_kernel(const float* __restrict__ x,
                                ushort* __restrict__ A, int n4) {
  const int stride = gridDim.x * blockDim.x;
  for (int i4 = blockIdx.x * blockDim.x + threadIdx.x; i4 < n4; i4 += stride) {
    const int i = i4 * 4;
    const int w = i % 224;
    const int t1 = i / 224;
    const int h = t1 % 224;
    const int t2 = t1 / 224;
    const int c = t2 % 3;
    const int b = t2 / 3;
    float4v v = *(const float4v*)(x + i);
    ushort4v u;
    u.x = f2bf(v.x); u.y = f2bf(v.y); u.z = f2bf(v.z); u.w = f2bf(v.w);
    const int m = b * 196 + (h >> 4) * 14 + (w >> 4);
    const int d = c * 256 + (h & 15) * 16 + (w & 15);
    *(ushort4v*)(A + m * Kdim + d) = u;
  }
}

// ---------------- GEMM: 2-phase double-buffered, global_load_lds staging ----------
// LDS logical [row][64] bf16; 16B chunk (row,cb) stored at chunk row*8 + (cb^(row&7)).
// global_load_lds writes linearly -> pre-swizzle the global source (same involution).
__global__ __launch_bounds__(256) void gemm2_kernel(
    const ushort* __restrict__ A, const ushort* __restrict__ Bw,
    const float* __restrict__ w_sf, const float* __restrict__ bias_out,
    float* __restrict__ out, uint* __restrict__ amax_bits) {
  __shared__ __align__(16) ushort As[2][BM * BK];
  __shared__ __align__(16) ushort Bs[2][BN * BK];

  const int t = threadIdx.x;
  // bijective XCD swizzle (NWG = 1176 = 8*147): XCD k owns swz in [147k,147k+147)
  // decompose swz = mb*6 + eb -> each XCD reads ~24 A-tiles x all 6 e-blocks (L2 reuse)
  const int orig = blockIdx.x;
  const int swz = (orig & 7) * (NWG / 8) + (orig >> 3);
  const int mb = swz / EB_TILES;
  const int eb = swz - mb * EB_TILES;
  const int m0 = mb * BM;
  const int e0 = eb * BN;

  // staging: linear LDS chunk c = r*256 + t; row = r*32 + (t>>3);
  // stored slot s = t&7; logical col cb = s ^ (row&7) = (t&7)^((t>>3)&7)
  const int cbs = (t & 7) ^ ((t >> 3) & 7);
  const ushort* ag = A + (size_t)(m0 + (t >> 3)) * Kdim + cbs * 8;
  const ushort* bg = Bw + (size_t)(e0 + (t >> 3)) * Kdim + cbs * 8;

  const int lane = t & 63;
  const int wv = t >> 6;
  const int wrow0 = (wv >> 1) * 64;
  const int wcol0 = (wv & 1) * 64;
  const int l15 = lane & 15, l4 = lane >> 4;
  int arow[4], brow[4];
#pragma unroll
  for (int i = 0; i < 4; ++i) {
    arow[i] = wrow0 + i * 16 + l15;
    brow[i] = wcol0 + i * 16 + l15;
  }

  f32x4 acc[4][4] = {};

  // prologue: stage tile 0 into buffer 0
#pragma unroll
  for (int r = 0; r < 4; ++r) {
    gload16(ag + r * 32 * Kdim, &As[0][(r * 256 + t) * 8]);
    gload16(bg + r * 32 * Kdim, &Bs[0][(r * 256 + t) * 8]);
  }
  __syncthreads();

#pragma unroll 2
  for (int kb = 0; kb < KSTEPS; ++kb) {
    const int cur = kb & 1;
    // issue next-tile loads FIRST (latency hides under this tile's compute)
    if (kb + 1 < KSTEPS) {
#pragma unroll
      for (int r = 0; r < 4; ++r) {
        gload16(ag + (kb + 1) * 64 + r * 32 * Kdim, &As[cur ^ 1][(r * 256 + t) * 8]);
        gload16(bg + (kb + 1) * 64 + r * 32 * Kdim, &Bs[cur ^ 1][(r * 256 + t) * 8]);
      }
    }
    // compute current tile
#pragma unroll
    for (int kk = 0; kk < 2; ++kk) {
      short8 a[4], b[4];
      const int cb = kk * 4 + l4;
#pragma unroll
      for (int i = 0; i < 4; ++i)
        a[i] = *(const short8*)&As[cur][arow[i] * 64 + ((cb ^ (arow[i] & 7)) << 3)];
#pragma unroll
      for (int i = 0; i < 4; ++i)
        b[i] = *(const short8*)&Bs[cur][brow[i] * 64 + ((cb ^ (brow[i] & 7)) << 3)];
#pragma unroll
      for (int mi = 0; mi < 4; ++mi)
#pragma unroll
        for (int ni = 0; ni < 4; ++ni)
          acc[mi][ni] = __builtin_amdgcn_mfma_f32_16x16x32_bf16(
              a[mi], b[ni], acc[mi][ni], 0, 0, 0);
    }
    // single barrier per K-step: drains prefetch (vmcnt) + guards buffer reuse
    __syncthreads();
  }

  float amax = 0.f;
#pragma unroll
  for (int ni = 0; ni < 4; ++ni) {
    const int e = e0 + wcol0 + ni * 16 + l15;
    const float s = w_sf[e], bo = bias_out[e];
#pragma unroll
    for (int mi = 0; mi < 4; ++mi) {
      const int mr = m0 + wrow0 + mi * 16 + l4 * 4;
#pragma unroll
      for (int q = 0; q < 4; ++q) {
        float v = acc[mi][ni][q] * s + bo;
        amax = fmaxf(amax, fabsf(v));
        out[(size_t)(mr + q) * Edim + e] = v;
      }
    }
  }
#pragma unroll
  for (int off = 32; off > 0; off >>= 1)
    amax = fmaxf(amax, __shfl_xor(amax, off));
  if (lane == 0) atomicMax(amax_bits, __float_as_uint(amax));
}

// ---------------- requantize in place + act_sf ----------------
__global__ void requant_kernel(float* __restrict__ out,
                               const uint* __restrict__ amax_bits,
                               float* __restrict__ sf_out, int n4) {
  const float mx = __uint_as_float(*amax_bits);
  const float act_sf = mx / 127.0f;
  const float inv = 127.0f / mx;
  const int idx = blockIdx.x * blockDim.x + threadIdx.x;
  if (idx == 0) *sf_out = act_sf;
  float4v* o = (float4v*)out;
  const int stride = gridDim.x * blockDim.x;
  for (int i = idx; i < n4; i += stride) {
    float4v v = o[i];
    v.x = rintf(v.x * inv) * act_sf;
    v.y = rintf(v.y * inv) * act_sf;
    v.z = rintf(v.z * inv) * act_sf;
    v.w = rintf(v.w * inv) * act_sf;
    o[i] = v;
  }
}

extern "C" void kernel_launch(void* const* d_in, const int* in_sizes, int n_in,
                              void* d_out, int out_size, void* d_ws, size_t ws_size,
                              hipStream_t stream) {
  const float* x = (const float*)d_in[0];
  const float* weight = (const float*)d_in[1];
  const float* bias = (const float*)d_in[2];
  const float* sfin = (const float*)d_in[3];
  float* out = (float*)d_out;

  char* ws = (char*)d_ws;
  uint* amax_bits = (uint*)(ws + WS_AMAX);
  float* w_sf = (float*)(ws + WS_WSF);
  float* bias_out = (float*)(ws + WS_BIAS);
  ushort* w_int = (ushort*)(ws + WS_WINT);
  ushort* A = (ushort*)(ws + WS_APAT);

  hipMemsetAsync(d_ws, 0, 4, stream);
  prep_kernel<<<Edim, 256, 0, stream>>>(weight, bias, sfin, w_int, w_sf, bias_out);

  const int n4 = (128 * 3 * 224 * 224) / 4;
  patchify_kernel<<<2048, 256, 0, stream>>>(x, A, n4);
  gemm2_kernel<<<NWG, 256, 0, stream>>>(A, w_int, w_sf, bias_out, out, amax_bits);

  const int n4o = (out_size - 1) / 4;
  requant_kernel<<<2048, 256, 0, stream>>>(out, amax_bits, out + (out_size - 1), n4o);
}